// Round 1
// baseline (1116.982 us; speedup 1.0000x reference)
//
#include <hip/hip_runtime.h>
#include <math.h>

#define NROWS 16384
#define KC    2048
#define DIM   512
#define BD    64
#define TD    256

// K1 tiling
#define R_   16     // rows per block
#define CT_  256    // codes per tile
#define DC_  16     // d-chunk
#define NT_  256    // threads

// d_out element offsets (all float32)
#define OUT_Q_OFF    1
#define OUT_P_OFF    (1 + 8388608)
#define OUT_IDX_OFF  (1 + 8388608 + 1)

// ws byte offsets
#define WS_COUNTS 0        // int[2048]        (zeroed each call)
#define WS_LOSS   8192     // float            (zeroed each call)
#define WS_W2D    8448     // double[2048]
#define WS_W2F    24832    // float[2048]
#define WS_IDX3   33024    // int4[16384]

// ---------------------------------------------------------------- w2 = ||W_k||^2
__global__ __launch_bounds__(256) void k_w2(const float* __restrict__ W,
                                            double* __restrict__ w2d,
                                            float* __restrict__ w2f) {
  int wave = threadIdx.x >> 6;
  int lane = threadIdx.x & 63;
  int k = blockIdx.x * 4 + wave;
  const float4* row = (const float4*)(W + k * DIM);
  float4 a = row[lane];
  float4 b = row[lane + 64];
  double acc = 0.0;
  acc += (double)a.x * a.x + (double)a.y * a.y + (double)a.z * a.z + (double)a.w * a.w;
  acc += (double)b.x * b.x + (double)b.y * b.y + (double)b.z * b.z + (double)b.w * b.w;
  for (int o = 32; o > 0; o >>= 1) acc += __shfl_down(acc, o);
  if (lane == 0) { w2d[k] = acc; w2f[k] = (float)acc; }
}

// ------------------------------------- K1: score GEMM + top-8 select + fp64 refine
__global__ __launch_bounds__(NT_) void k_select(
    const float* __restrict__ x, const float* __restrict__ W,
    const float* __restrict__ w2f, const double* __restrict__ w2d,
    int4* __restrict__ idx3, int* __restrict__ counts,
    float* __restrict__ out_idx)
{
  __shared__ float xs[R_][520];                 // x rows, padded stride
  __shared__ __align__(16) char ubuf[24576];    // union: wt tile / candidate dump
  __shared__ int    top8i[R_][8];
  __shared__ double sc8[R_][8];

  float (*wt)[260] = (float (*)[260])ubuf;      // transposed W tile [d][c], 16x260
  float* candF = (float*)ubuf;
  int*   candI = (int*)ubuf;

  const int tid = threadIdx.x;
  const int n0  = blockIdx.x * R_;
  const int b   = n0 >> 8;
  const int t0  = n0 & 255;

  // Phase A: stage 16 x-rows ([B,D,T] layout -> strided gather, coalesced in t)
  #pragma unroll
  for (int it = 0; it < (R_ * DIM) / NT_; ++it) {
    int flat = tid + it * NT_;
    int d  = flat >> 4;
    int rr = flat & 15;
    xs[rr][d] = x[((b * DIM + d) << 8) + t0 + rr];
  }

  const int tx = tid & 63;   // 64 code-groups of 4
  const int ty = tid >> 6;   // 4 row-groups of 4
  const int r0 = ty * 4;
  const int c0 = tx * 4;

  float ts[4][3]; int ti[4][3];   // per-thread top-3 per row (score ascending)
  #pragma unroll
  for (int r = 0; r < 4; ++r)
    #pragma unroll
    for (int j = 0; j < 3; ++j) { ts[r][j] = 3.0e38f; ti[r][j] = 0; }

  for (int ct = 0; ct < KC / CT_; ++ct) {
    float acc[4][4];
    #pragma unroll
    for (int r = 0; r < 4; ++r)
      #pragma unroll
      for (int c = 0; c < 4; ++c) acc[r][c] = 0.0f;

    for (int dch = 0; dch < DIM / DC_; ++dch) {
      __syncthreads();
      // stage wt[d][c] transposed (coalesced global read along d, scatter to LDS)
      #pragma unroll
      for (int jj = 0; jj < 4; ++jj) {
        int flat = tid + jj * NT_;          // 0..1023 float4 units
        int cl  = flat >> 2;
        int dq4 = flat & 3;
        float4 v = *(const float4*)&W[(ct * CT_ + cl) * DIM + dch * DC_ + dq4 * 4];
        int dd = dq4 * 4;
        wt[dd + 0][cl] = v.x;
        wt[dd + 1][cl] = v.y;
        wt[dd + 2][cl] = v.z;
        wt[dd + 3][cl] = v.w;
      }
      __syncthreads();
      #pragma unroll
      for (int dq = 0; dq < DC_ / 4; ++dq) {
        int dbase = dch * DC_ + dq * 4;
        float xr[4][4], wc[4][4];
        #pragma unroll
        for (int r = 0; r < 4; ++r) {
          float4 v = *(const float4*)&xs[r0 + r][dbase];   // broadcast read
          xr[r][0] = v.x; xr[r][1] = v.y; xr[r][2] = v.z; xr[r][3] = v.w;
        }
        #pragma unroll
        for (int dd = 0; dd < 4; ++dd) {
          float4 v = *(const float4*)&wt[dq * 4 + dd][c0]; // contiguous b128
          wc[dd][0] = v.x; wc[dd][1] = v.y; wc[dd][2] = v.z; wc[dd][3] = v.w;
        }
        #pragma unroll
        for (int r = 0; r < 4; ++r)
          #pragma unroll
          for (int c = 0; c < 4; ++c)
            #pragma unroll
            for (int dd = 0; dd < 4; ++dd)
              acc[r][c] = fmaf(xr[r][dd], wc[dd][c], acc[r][c]);
      }
    }
    // fold tile scores into per-thread top-3 (score = w2 - 2*dot; x^2 is row-const)
    float4 w2v = *(const float4*)&w2f[ct * CT_ + c0];
    float w2a[4] = {w2v.x, w2v.y, w2v.z, w2v.w};
    #pragma unroll
    for (int r = 0; r < 4; ++r) {
      #pragma unroll
      for (int c = 0; c < 4; ++c) {
        float s = fmaf(-2.0f, acc[r][c], w2a[c]);
        int code = ct * CT_ + c0 + c;
        if (s < ts[r][2]) {
          ts[r][2] = s; ti[r][2] = code;
          if (ts[r][2] < ts[r][1]) {
            float tf = ts[r][1]; ts[r][1] = ts[r][2]; ts[r][2] = tf;
            int   t2 = ti[r][1]; ti[r][1] = ti[r][2]; ti[r][2] = t2;
          }
          if (ts[r][1] < ts[r][0]) {
            float tf = ts[r][0]; ts[r][0] = ts[r][1]; ts[r][1] = tf;
            int   t2 = ti[r][0]; ti[r][0] = ti[r][1]; ti[r][1] = t2;
          }
        }
      }
    }
  }

  __syncthreads();
  // Phase C: dump candidates (16 rows x 64 threads x 3) into ubuf
  #pragma unroll
  for (int r = 0; r < 4; ++r) {
    int rr = r0 + r;
    #pragma unroll
    for (int j = 0; j < 3; ++j) {
      int slot = (rr * 192 + tx * 3 + j) * 2;
      candF[slot]     = ts[r][j];
      candI[slot + 1] = ti[r][j];
    }
  }
  __syncthreads();

  // merge 192 candidates -> top-8 per row (one thread per row)
  if (tid < R_) {
    int rr = tid;
    float s8[8]; int i8[8];
    #pragma unroll
    for (int k = 0; k < 8; ++k) { s8[k] = 3.0e38f; i8[k] = 0x7fffffff; }
    for (int e = 0; e < 192; ++e) {
      int slot = (rr * 192 + e) * 2;
      float s  = candF[slot];
      int   ic = candI[slot + 1];
      if (s < s8[7]) {
        s8[7] = s; i8[7] = ic;
        #pragma unroll
        for (int k = 7; k >= 1; --k) {
          if (s8[k] < s8[k - 1]) {
            float tf = s8[k]; s8[k] = s8[k-1]; s8[k-1] = tf;
            int   t2 = i8[k]; i8[k] = i8[k-1]; i8[k-1] = t2;
          }
        }
      }
    }
    #pragma unroll
    for (int k = 0; k < 8; ++k) top8i[rr][k] = i8[k];
  }
  __syncthreads();

  // Phase D: exact fp64 re-score of 8 candidates per row
  if (tid < R_ * 8) {
    int rr = tid >> 3, j = tid & 7;
    int code = top8i[rr][j];
    const float4* wr4 = (const float4*)(W + code * DIM);
    const float4* xr4 = (const float4*)&xs[rr][0];
    double d0 = 0.0, d1 = 0.0, d2 = 0.0, d3 = 0.0;
    for (int dd = 0; dd < DIM / 4; ++dd) {
      float4 wv = wr4[dd];
      float4 xv = xr4[dd];
      d0 = fma((double)xv.x, (double)wv.x, d0);
      d1 = fma((double)xv.y, (double)wv.y, d1);
      d2 = fma((double)xv.z, (double)wv.z, d2);
      d3 = fma((double)xv.w, (double)wv.w, d3);
    }
    double dot = (d0 + d1) + (d2 + d3);
    sc8[rr][j] = w2d[code] - 2.0 * dot;
  }
  __syncthreads();

  // final per-row: sort 8 by (score, index) ascending == jax.lax.top_k(-dist) order
  if (tid < R_) {
    int rr = tid;
    double sd[8]; int id_[8];
    #pragma unroll
    for (int k = 0; k < 8; ++k) { sd[k] = sc8[rr][k]; id_[k] = top8i[rr][k]; }
    #pragma unroll
    for (int i = 0; i < 7; ++i)
      #pragma unroll
      for (int jj = 0; jj < 7; ++jj) {
        if (jj < 7 - i) {
          bool sw = (sd[jj] > sd[jj+1]) ||
                    (sd[jj] == sd[jj+1] && id_[jj] > id_[jj+1]);
          if (sw) {
            double td = sd[jj]; sd[jj] = sd[jj+1]; sd[jj+1] = td;
            int    tt = id_[jj]; id_[jj] = id_[jj+1]; id_[jj+1] = tt;
          }
        }
      }
    int n = n0 + rr;
    idx3[n] = make_int4(id_[0], id_[1], id_[2], 0);
    out_idx[n] = (float)id_[2];
    atomicAdd(&counts[id_[0]], 1);
    atomicAdd(&counts[id_[1]], 1);
    atomicAdd(&counts[id_[2]], 1);
  }
}

// --------------------- K3: quantized_st (native [B,D,T] layout) + fused loss sum
__global__ __launch_bounds__(256) void k_qout(
    const float* __restrict__ x, const float* __restrict__ W,
    const int4* __restrict__ idx3, float* __restrict__ out,
    float* __restrict__ loss_acc)
{
  int t = threadIdx.x;
  int d = blockIdx.x;
  int b = blockIdx.y;
  int n = (b << 8) + t;
  int4 ii = idx3[n];
  float q = (W[ii.x * DIM + d] + W[ii.y * DIM + d] + W[ii.z * DIM + d]) * (1.0f / 3.0f);
  int off = ((b * DIM + d) << 8) + t;
  float xv = x[off];
  float diff = q - xv;                 // quantized - inp
  out[OUT_Q_OFF + off] = xv + diff;    // straight-through value
  float v = diff * diff;
  for (int o = 32; o > 0; o >>= 1) v += __shfl_down(v, o);
  __shared__ float ps[4];
  if ((t & 63) == 0) ps[t >> 6] = v;
  __syncthreads();
  if (t == 0) atomicAdd(loss_acc, (ps[0] + ps[1]) + (ps[2] + ps[3]));
}

// -------------------------------------------- K4: loss + perplexity finalization
__global__ __launch_bounds__(256) void k_final(
    const int* __restrict__ counts, const float* __restrict__ loss_acc,
    float* __restrict__ out)
{
  int tid = threadIdx.x;
  float ent = 0.0f;
  for (int k = tid; k < KC; k += 256) {
    float p = (float)counts[k] * (1.0f / 16384.0f);
    ent += p * logf(p + 1e-10f);
  }
  for (int o = 32; o > 0; o >>= 1) ent += __shfl_down(ent, o);
  __shared__ float ps[4];
  if ((tid & 63) == 0) ps[tid >> 6] = ent;
  __syncthreads();
  if (tid == 0) {
    float total = (ps[0] + ps[1]) + (ps[2] + ps[3]);
    // loss = q_latent + 0.25*e_latent = 1.25 * mean((q-x)^2)
    out[0] = 1.25f * loss_acc[0] * (1.0f / 8388608.0f);
    out[OUT_P_OFF] = expf(-total);
  }
}

extern "C" void kernel_launch(void* const* d_in, const int* in_sizes, int n_in,
                              void* d_out, int out_size, void* d_ws, size_t ws_size,
                              hipStream_t stream) {
  const float* x = (const float*)d_in[0];
  const float* W = (const float*)d_in[1];
  float* out = (float*)d_out;
  char* ws = (char*)d_ws;
  int*    counts   = (int*)(ws + WS_COUNTS);
  float*  loss_acc = (float*)(ws + WS_LOSS);
  double* w2d      = (double*)(ws + WS_W2D);
  float*  w2f      = (float*)(ws + WS_W2F);
  int4*   idx3     = (int4*)(ws + WS_IDX3);

  hipMemsetAsync(ws, 0, 8448, stream);   // counts + loss accumulator
  k_w2<<<KC / 4, 256, 0, stream>>>(W, w2d, w2f);
  k_select<<<NROWS / R_, NT_, 0, stream>>>(x, W, w2f, w2d, idx3, counts,
                                           out + OUT_IDX_OFF);
  k_qout<<<dim3(DIM, BD), 256, 0, stream>>>(x, W, idx3, out, loss_acc);
  k_final<<<1, 256, 0, stream>>>(counts, loss_acc, out);
}

// Round 2
// 271.619 us; speedup vs baseline: 4.1123x; 4.1123x over previous
//
#include <hip/hip_runtime.h>
#include <math.h>

typedef short  short8  __attribute__((ext_vector_type(8)));
typedef float  floatx4 __attribute__((ext_vector_type(4)));

#define NROWS 16384
#define KC    2048
#define DIM   512
#define MB    32      // rows per k_main block

// d_out element offsets (all float32): loss, q[8388608], perplexity, idx[16384]
#define OUT_Q_OFF    1
#define OUT_P_OFF    (1 + 8388608)
#define OUT_IDX_OFF  (1 + 8388608 + 1)

// ws byte offsets
#define WS_COUNTS 0        // int[2048]   (zeroed each call)
#define WS_LOSS   8192     // float       (zeroed each call)
#define WS_W2D    8448     // double[2048]
#define WS_W2F    24832    // float[2048]
#define WS_WB     33024    // ushort[2048*512]  bf16 codebook (2 MB)

__device__ __forceinline__ unsigned short f2bf(float f) {
  union { float f; unsigned int u; } v; v.f = f;
  unsigned int u = v.u;
  return (unsigned short)((u + 0x7fffu + ((u >> 16) & 1u)) >> 16);
}

// ---------------- k_prep: w2 (fp64+fp32) and bf16 codebook conversion
__global__ __launch_bounds__(256) void k_prep(const float* __restrict__ W,
                                              double* __restrict__ w2d,
                                              float* __restrict__ w2f,
                                              unsigned short* __restrict__ Wb) {
  int wave = threadIdx.x >> 6;
  int lane = threadIdx.x & 63;
  int k = blockIdx.x * 4 + wave;
  const float4* row = (const float4*)(W + (size_t)k * DIM);
  float4 a = row[lane];
  float4 b = row[lane + 64];
  unsigned short* dst = Wb + (size_t)k * DIM;
  dst[lane*4 + 0] = f2bf(a.x); dst[lane*4 + 1] = f2bf(a.y);
  dst[lane*4 + 2] = f2bf(a.z); dst[lane*4 + 3] = f2bf(a.w);
  dst[256 + lane*4 + 0] = f2bf(b.x); dst[256 + lane*4 + 1] = f2bf(b.y);
  dst[256 + lane*4 + 2] = f2bf(b.z); dst[256 + lane*4 + 3] = f2bf(b.w);
  double acc = 0.0;
  acc += (double)a.x*a.x + (double)a.y*a.y + (double)a.z*a.z + (double)a.w*a.w;
  acc += (double)b.x*b.x + (double)b.y*b.y + (double)b.z*b.z + (double)b.w*b.w;
  for (int o = 32; o > 0; o >>= 1) acc += __shfl_down(acc, o);
  if (lane == 0) { w2d[k] = acc; w2f[k] = (float)acc; }
}

// ---------------- k_main: bf16 MFMA coarse scores -> top-8 -> fp64 refine
//                  -> idx/counts + fused quantize/loss epilogue
__global__ __launch_bounds__(256) void k_main(
    const float* __restrict__ x, const float* __restrict__ W,
    const unsigned short* __restrict__ Wb,
    const float* __restrict__ w2f, const double* __restrict__ w2d,
    int* __restrict__ counts, float* __restrict__ out,
    float* __restrict__ loss_acc)
{
  // ubuf: W tile [2 halves][64 codes][72 pad] ushort (18432 B) during GEMM,
  //       then candidate dump (32 rows x 96 x {float,int} = 24576 B).
  __shared__ __align__(16) char ubuf[24576];
  unsigned short (*Wt)[64][72] = (unsigned short (*)[64][72])ubuf;
  float* candF = (float*)ubuf;
  int*   candI = (int*)(ubuf + 12288);
  __shared__ int    top8i[MB][8];
  __shared__ double sc8[MB][8];
  __shared__ int4   idx3s[MB];
  __shared__ float  lred[4];

  const int tid  = threadIdx.x;
  const int w    = tid >> 6;          // wave id
  const int lane = tid & 63;
  const int q    = lane >> 4;         // quad
  const int l15  = lane & 15;
  const int rg   = w & 1;             // row group (16 rows each)
  const int ch   = w >> 1;            // code half (1024 codes each)
  const int n0   = blockIdx.x * MB;
  const int b    = n0 >> 8;
  const int t0   = n0 & 255;

  // ---- Phase A: x rows -> bf16 A-fragments in registers (16 ksteps x 8)
  short8 af[16];
  {
    const float* xb = x + (size_t)b * DIM * 256 + t0 + rg * 16 + l15;
    #pragma unroll
    for (int s = 0; s < 16; ++s)
      #pragma unroll
      for (int j = 0; j < 8; ++j) {
        int d = s * 32 + q * 8 + j;
        af[s][j] = (short)f2bf(xb[(size_t)d * 256]);
      }
  }

  float ts[4][3]; int ti[4][3];       // per-lane top-3 per row-reg
  #pragma unroll
  for (int i = 0; i < 4; ++i)
    #pragma unroll
    for (int j = 0; j < 3; ++j) { ts[i][j] = 3.0e38f; ti[i][j] = 0; }

  // ---- Phase B: MFMA over the wave's 1024-code half, 64 codes per ct
  for (int ct = 0; ct < 16; ++ct) {
    floatx4 acc[4];
    #pragma unroll
    for (int nt = 0; nt < 4; ++nt) { floatx4 z = {0.f,0.f,0.f,0.f}; acc[nt] = z; }

    #pragma unroll
    for (int kc = 0; kc < 8; ++kc) {
      __syncthreads();
      { // cooperative stage: both halves' [64 codes][64 dims] bf16 tiles
        int half = tid >> 7, tloc = tid & 127;
        #pragma unroll
        for (int j = 0; j < 4; ++j) {
          int u  = tloc + j * 128;
          int c  = u >> 3, c8 = u & 7;
          const int4* src = (const int4*)(Wb +
              (size_t)(half * 1024 + ct * 64 + c) * DIM + kc * 64 + c8 * 8);
          *(int4*)&Wt[half][c][c8 * 8] = *src;
        }
      }
      __syncthreads();
      #pragma unroll
      for (int ks = 0; ks < 2; ++ks) {
        short8 a = af[kc * 2 + ks];
        #pragma unroll
        for (int nt = 0; nt < 4; ++nt) {
          short8 bfr = *(short8*)&Wt[ch][nt * 16 + l15][ks * 32 + q * 8];
          acc[nt] = __builtin_amdgcn_mfma_f32_16x16x32_bf16(a, bfr, acc[nt], 0, 0, 0);
        }
      }
    }

    // fold: s = w2 - 2*dot  (row m = q*4 + i, col code = cb + nt*16 + l15)
    int cb = ch * 1024 + ct * 64;
    #pragma unroll
    for (int nt = 0; nt < 4; ++nt) {
      int code = cb + nt * 16 + l15;
      float w2 = w2f[code];
      #pragma unroll
      for (int i = 0; i < 4; ++i) {
        float s = fmaf(-2.0f, acc[nt][i], w2);
        if (s < ts[i][2]) {
          ts[i][2] = s; ti[i][2] = code;
          if (ts[i][2] < ts[i][1]) {
            float tf = ts[i][1]; ts[i][1] = ts[i][2]; ts[i][2] = tf;
            int   t2 = ti[i][1]; ti[i][1] = ti[i][2]; ti[i][2] = t2;
          }
          if (ts[i][1] < ts[i][0]) {
            float tf = ts[i][0]; ts[i][0] = ts[i][1]; ts[i][1] = tf;
            int   t2 = ti[i][0]; ti[i][0] = ti[i][1]; ti[i][1] = t2;
          }
        }
      }
    }
  }

  __syncthreads();   // Wt no longer needed; ubuf becomes candidate dump

  // ---- Phase C: dump per-lane top-3, merge 96 -> top-8 per row
  #pragma unroll
  for (int i = 0; i < 4; ++i) {
    int rloc = rg * 16 + q * 4 + i;
    #pragma unroll
    for (int j = 0; j < 3; ++j) {
      int slot = rloc * 96 + ch * 48 + l15 * 3 + j;
      candF[slot] = ts[i][j];
      candI[slot] = ti[i][j];
    }
  }
  __syncthreads();

  if (tid < MB) {
    float s8[8]; int i8[8];
    #pragma unroll
    for (int k = 0; k < 8; ++k) { s8[k] = 3.0e38f; i8[k] = 0x7fffffff; }
    for (int e = 0; e < 96; ++e) {
      float s = candF[tid * 96 + e];
      int   c = candI[tid * 96 + e];
      if (s < s8[7]) {
        s8[7] = s; i8[7] = c;
        #pragma unroll
        for (int k = 7; k >= 1; --k)
          if (s8[k] < s8[k - 1]) {
            float tf = s8[k]; s8[k] = s8[k-1]; s8[k-1] = tf;
            int   t2 = i8[k]; i8[k] = i8[k-1]; i8[k-1] = t2;
          }
      }
    }
    #pragma unroll
    for (int k = 0; k < 8; ++k) top8i[tid][k] = i8[k];
  }
  __syncthreads();

  // ---- Phase D: exact fp64 re-score of 8 candidates per row
  {
    int rr = tid >> 3, j = tid & 7;
    int code = top8i[rr][j];
    const float4* wr4 = (const float4*)(W + (size_t)code * DIM);
    const float*  xr  = x + (size_t)b * DIM * 256 + t0 + rr;
    double d0 = 0.0, d1 = 0.0, d2 = 0.0, d3 = 0.0;
    for (int d4 = 0; d4 < 128; ++d4) {
      float4 wv = wr4[d4];
      float x0 = xr[(size_t)(d4*4 + 0) * 256];
      float x1 = xr[(size_t)(d4*4 + 1) * 256];
      float x2 = xr[(size_t)(d4*4 + 2) * 256];
      float x3 = xr[(size_t)(d4*4 + 3) * 256];
      d0 = fma((double)x0, (double)wv.x, d0);
      d1 = fma((double)x1, (double)wv.y, d1);
      d2 = fma((double)x2, (double)wv.z, d2);
      d3 = fma((double)x3, (double)wv.w, d3);
    }
    sc8[rr][j] = w2d[code] - 2.0 * ((d0 + d1) + (d2 + d3));
  }
  __syncthreads();

  // ---- final order: sort 8 by (score, index) asc == top_k(-dist) order
  if (tid < MB) {
    double sd[8]; int id_[8];
    #pragma unroll
    for (int k = 0; k < 8; ++k) { sd[k] = sc8[tid][k]; id_[k] = top8i[tid][k]; }
    #pragma unroll
    for (int i = 0; i < 7; ++i)
      #pragma unroll
      for (int jj = 0; jj < 7; ++jj)
        if (jj < 7 - i) {
          bool sw = (sd[jj] > sd[jj+1]) ||
                    (sd[jj] == sd[jj+1] && id_[jj] > id_[jj+1]);
          if (sw) {
            double td = sd[jj]; sd[jj] = sd[jj+1]; sd[jj+1] = td;
            int    tt = id_[jj]; id_[jj] = id_[jj+1]; id_[jj+1] = tt;
          }
        }
    int n = n0 + tid;
    idx3s[tid] = make_int4(id_[0], id_[1], id_[2], 0);
    out[OUT_IDX_OFF + n] = (float)id_[2];
    atomicAdd(&counts[id_[0]], 1);
    atomicAdd(&counts[id_[1]], 1);
    atomicAdd(&counts[id_[2]], 1);
  }
  __syncthreads();

  // ---- Phase E: fused quantize + straight-through + loss
  {
    int rr = tid & 31, g = tid >> 5;       // 8 d-groups of 64 dims
    int4 ii = idx3s[rr];
    const float4* w0 = (const float4*)(W + (size_t)ii.x * DIM);
    const float4* w1 = (const float4*)(W + (size_t)ii.y * DIM);
    const float4* w2 = (const float4*)(W + (size_t)ii.z * DIM);
    const float*  xr = x + (size_t)b * DIM * 256 + t0 + rr;
    float* outq = out + OUT_Q_OFF + (size_t)b * DIM * 256 + t0 + rr;
    float lsum = 0.0f;
    #pragma unroll 4
    for (int d4 = 0; d4 < 16; ++d4) {
      int idx4 = g * 16 + d4;
      float4 a0 = w0[idx4], a1 = w1[idx4], a2 = w2[idx4];
      float qv[4] = { (a0.x + a1.x + a2.x) * (1.0f/3.0f),
                      (a0.y + a1.y + a2.y) * (1.0f/3.0f),
                      (a0.z + a1.z + a2.z) * (1.0f/3.0f),
                      (a0.w + a1.w + a2.w) * (1.0f/3.0f) };
      #pragma unroll
      for (int e = 0; e < 4; ++e) {
        size_t off = (size_t)(idx4 * 4 + e) * 256;
        float xv = xr[off];
        float diff = qv[e] - xv;             // quantized - inp
        outq[off] = xv + diff;               // straight-through value
        lsum += diff * diff;
      }
    }
    for (int o = 32; o > 0; o >>= 1) lsum += __shfl_down(lsum, o);
    if (lane == 0) lred[w] = lsum;
  }
  __syncthreads();
  if (tid == 0)
    atomicAdd(loss_acc, (lred[0] + lred[1]) + (lred[2] + lred[3]));
}

// ---------------- k_final: loss + perplexity
__global__ __launch_bounds__(256) void k_final(
    const int* __restrict__ counts, const float* __restrict__ loss_acc,
    float* __restrict__ out)
{
  int tid = threadIdx.x;
  float ent = 0.0f;
  for (int k = tid; k < KC; k += 256) {
    float p = (float)counts[k] * (1.0f / 16384.0f);
    ent += p * logf(p + 1e-10f);
  }
  for (int o = 32; o > 0; o >>= 1) ent += __shfl_down(ent, o);
  __shared__ float ps[4];
  if ((tid & 63) == 0) ps[tid >> 6] = ent;
  __syncthreads();
  if (tid == 0) {
    float total = (ps[0] + ps[1]) + (ps[2] + ps[3]);
    out[0] = 1.25f * loss_acc[0] * (1.0f / 8388608.0f);  // q + 0.25*e latent
    out[OUT_P_OFF] = expf(-total);
  }
}

extern "C" void kernel_launch(void* const* d_in, const int* in_sizes, int n_in,
                              void* d_out, int out_size, void* d_ws, size_t ws_size,
                              hipStream_t stream) {
  const float* x = (const float*)d_in[0];
  const float* W = (const float*)d_in[1];
  float* out = (float*)d_out;
  char* ws = (char*)d_ws;
  int*            counts   = (int*)(ws + WS_COUNTS);
  float*          loss_acc = (float*)(ws + WS_LOSS);
  double*         w2d      = (double*)(ws + WS_W2D);
  float*          w2f      = (float*)(ws + WS_W2F);
  unsigned short* Wb       = (unsigned short*)(ws + WS_WB);

  hipMemsetAsync(ws, 0, 8448, stream);   // counts + loss accumulator
  k_prep<<<KC / 4, 256, 0, stream>>>(W, w2d, w2f, Wb);
  k_main<<<NROWS / MB, 256, 0, stream>>>(x, W, Wb, w2f, w2d, counts, out, loss_acc);
  k_final<<<1, 256, 0, stream>>>(counts, loss_acc, out);
}

// Round 3
// 217.106 us; speedup vs baseline: 5.1449x; 1.2511x over previous
//
#include <hip/hip_runtime.h>
#include <math.h>

typedef short  short8  __attribute__((ext_vector_type(8)));
typedef float  floatx4 __attribute__((ext_vector_type(4)));

#define NROWS 16384
#define KC    2048
#define DIM   512
#define MB    32      // rows per k_main block

// d_out element offsets (all float32): loss, q[8388608], perplexity, idx[16384]
#define OUT_Q_OFF    1
#define OUT_P_OFF    (1 + 8388608)
#define OUT_IDX_OFF  (1 + 8388608 + 1)

// ws byte offsets
#define WS_COUNTS 0        // int[2048]   (zeroed each call)
#define WS_LOSS   8192     // float       (zeroed each call)
#define WS_W2D    8448     // double[2048]
#define WS_W2F    24832    // float[2048]
#define WS_WB     33024    // ushort[2048*512] bf16 codebook, FRAGMENT-ORDERED (2 MB)

__device__ __forceinline__ unsigned short f2bf(float f) {
  union { float f; unsigned int u; } v; v.f = f;
  unsigned int u = v.u;
  return (unsigned short)((u + 0x7fffu + ((u >> 16) & 1u)) >> 16);
}

// monotone pack: fp32 score -> ascending uint, low 11 bits replaced by code
__device__ __forceinline__ unsigned int packsc(float s, int code) {
  union { float f; unsigned int u; } v; v.f = s;
  unsigned int u = v.u;
  u = (u & 0x80000000u) ? ~u : (u | 0x80000000u);
  return (u & 0xFFFFF800u) | (unsigned int)code;
}

__device__ __forceinline__ void ins3(unsigned int* t, unsigned int v) {
  if (v < t[2]) {
    t[2] = v;
    if (t[2] < t[1]) { unsigned int tmp = t[1]; t[1] = t[2]; t[2] = tmp; }
    if (t[1] < t[0]) { unsigned int tmp = t[0]; t[0] = t[1]; t[1] = tmp; }
  }
}

// ---------------- k_w2: ||W_k||^2 in fp64 + fp32
__global__ __launch_bounds__(256) void k_w2(const float* __restrict__ W,
                                            double* __restrict__ w2d,
                                            float* __restrict__ w2f) {
  int wave = threadIdx.x >> 6;
  int lane = threadIdx.x & 63;
  int k = blockIdx.x * 4 + wave;
  const float4* row = (const float4*)(W + (size_t)k * DIM);
  float4 a = row[lane];
  float4 b = row[lane + 64];
  double acc = 0.0;
  acc += (double)a.x*a.x + (double)a.y*a.y + (double)a.z*a.z + (double)a.w*a.w;
  acc += (double)b.x*b.x + (double)b.y*b.y + (double)b.z*b.z + (double)b.w*b.w;
  for (int o = 32; o > 0; o >>= 1) acc += __shfl_down(acc, o);
  if (lane == 0) { w2d[k] = acc; w2f[k] = (float)acc; }
}

// ---------------- k_reorder: W -> bf16 codebook in MFMA B-fragment order.
// frag f = c16*16 + ks (c16: 16-code tile, ks: 32-dim k-step), 1 KB each.
// lane (q=lane>>4, l15=lane&15) slot holds W[c16*16+l15][ks*32+q*8 .. +8).
__global__ __launch_bounds__(256) void k_reorder(const float* __restrict__ W,
                                                 unsigned short* __restrict__ Wb) {
  int gid  = blockIdx.x * 256 + threadIdx.x;   // 131072 total
  int lane = gid & 63;
  int f    = gid >> 6;                          // 0..2047
  int c16  = f >> 4, ks = f & 15;
  int l15  = lane & 15, q = lane >> 4;
  const float* src = W + (size_t)(c16 * 16 + l15) * DIM + ks * 32 + q * 8;
  float4 a = *(const float4*)src;
  float4 b = *(const float4*)(src + 4);
  short8 v;
  v[0] = (short)f2bf(a.x); v[1] = (short)f2bf(a.y);
  v[2] = (short)f2bf(a.z); v[3] = (short)f2bf(a.w);
  v[4] = (short)f2bf(b.x); v[5] = (short)f2bf(b.y);
  v[6] = (short)f2bf(b.z); v[7] = (short)f2bf(b.w);
  *(short8*)(Wb + (size_t)f * 512 + lane * 8) = v;
}

// ---------------- k_main: barrier-free bf16 MFMA streaming -> top-8 -> fp64
//                  refine -> idx/counts + fused quantize/loss epilogue
__global__ __launch_bounds__(256, 2) void k_main(
    const float* __restrict__ x, const float* __restrict__ W,
    const unsigned short* __restrict__ Wb,
    const float* __restrict__ w2f, const double* __restrict__ w2d,
    int* __restrict__ counts, float* __restrict__ out,
    float* __restrict__ loss_acc)
{
  __shared__ unsigned int candU[MB * 192];   // 24 KB packed candidates
  __shared__ unsigned int ps8[MB][8][8];     // 8 KB partial top-8
  __shared__ int    top8i[MB][8];
  __shared__ double sc8[MB][8];
  __shared__ int4   idx3s[MB];
  __shared__ float  lred[4];

  const int tid  = threadIdx.x;
  const int w    = tid >> 6;          // wave id: owns codes [w*512, w*512+512)
  const int lane = tid & 63;
  const int q    = lane >> 4;
  const int l15  = lane & 15;
  const int n0   = blockIdx.x * MB;
  const int b    = n0 >> 8;
  const int t0   = n0 & 255;

  // ---- Phase A: 32 rows -> bf16 A-fragments in registers (2 rowsets x 16 ksteps)
  short8 af[2][16];
  {
    const float* x0 = x + (size_t)b * DIM * 256 + t0 + l15;
    #pragma unroll
    for (int rs = 0; rs < 2; ++rs)
      #pragma unroll
      for (int s = 0; s < 16; ++s) {
        short8 v;
        #pragma unroll
        for (int j = 0; j < 8; ++j) {
          int d = s * 32 + q * 8 + j;
          v[j] = (short)f2bf(x0[(size_t)d * 256 + rs * 16]);
        }
        af[rs][s] = v;
      }
  }

  unsigned int ts[2][4][3];   // packed top-3 per (rowset, acc-reg)
  #pragma unroll
  for (int rs = 0; rs < 2; ++rs)
    #pragma unroll
    for (int i = 0; i < 4; ++i)
      #pragma unroll
      for (int j = 0; j < 3; ++j) ts[rs][i][j] = 0xFFFFFFFFu;

  // ---- Phase B: barrier-free GEMM. Each wave streams its 512 KB of
  //      fragment-ordered Wb straight into an 8-deep register ring.
  {
    const unsigned short* base = Wb + (size_t)(w * 512) * 512 + lane * 8;
    short8 ring[8];
    #pragma unroll
    for (int p = 0; p < 8; ++p)
      ring[p] = *(const short8*)(base + (size_t)p * 512);

    for (int ct = 0; ct < 32; ++ct) {
      floatx4 acc0 = {0.f, 0.f, 0.f, 0.f};
      floatx4 acc1 = {0.f, 0.f, 0.f, 0.f};
      #pragma unroll
      for (int ks = 0; ks < 16; ++ks) {
        int it = ct * 16 + ks;
        int nf = (it + 8 < 512) ? (it + 8) : 511;   // wave-uniform clamp
        short8 bfr = ring[ks & 7];
        ring[ks & 7] = *(const short8*)(base + (size_t)nf * 512);
        acc0 = __builtin_amdgcn_mfma_f32_16x16x32_bf16(af[0][ks], bfr, acc0, 0, 0, 0);
        acc1 = __builtin_amdgcn_mfma_f32_16x16x32_bf16(af[1][ks], bfr, acc1, 0, 0, 0);
      }
      int code = (w * 32 + ct) * 16 + l15;
      float w2 = w2f[code];
      #pragma unroll
      for (int i = 0; i < 4; ++i) {
        ins3(ts[0][i], packsc(fmaf(-2.0f, acc0[i], w2), code));
        ins3(ts[1][i], packsc(fmaf(-2.0f, acc1[i], w2), code));
      }
    }
  }

  // ---- Phase C: dump packed candidates, two-stage merge -> top-8 per row
  #pragma unroll
  for (int rs = 0; rs < 2; ++rs)
    #pragma unroll
    for (int i = 0; i < 4; ++i) {
      int row = rs * 16 + q * 4 + i;
      #pragma unroll
      for (int j = 0; j < 3; ++j)
        candU[row * 192 + w * 48 + l15 * 3 + j] = ts[rs][i][j];
    }
  __syncthreads();

  {
    int row = tid >> 3, sl = tid & 7;
    unsigned int s8[8];
    #pragma unroll
    for (int k = 0; k < 8; ++k) s8[k] = 0xFFFFFFFFu;
    for (int e = 0; e < 24; ++e) {
      unsigned int v = candU[row * 192 + sl * 24 + e];
      if (v < s8[7]) {
        s8[7] = v;
        #pragma unroll
        for (int k = 7; k >= 1; --k)
          if (s8[k] < s8[k - 1]) { unsigned int t = s8[k-1]; s8[k-1] = s8[k]; s8[k] = t; }
      }
    }
    #pragma unroll
    for (int k = 0; k < 8; ++k) ps8[row][sl][k] = s8[k];
  }
  __syncthreads();

  if (tid < MB) {
    unsigned int s8[8];
    #pragma unroll
    for (int k = 0; k < 8; ++k) s8[k] = 0xFFFFFFFFu;
    const unsigned int* src = &ps8[tid][0][0];
    for (int e = 0; e < 64; ++e) {
      unsigned int v = src[e];
      if (v < s8[7]) {
        s8[7] = v;
        #pragma unroll
        for (int k = 7; k >= 1; --k)
          if (s8[k] < s8[k - 1]) { unsigned int t = s8[k-1]; s8[k-1] = s8[k]; s8[k] = t; }
      }
    }
    #pragma unroll
    for (int k = 0; k < 8; ++k) top8i[tid][k] = (int)(s8[k] & 0x7FFu);
  }
  __syncthreads();

  // ---- Phase D: exact fp64 re-score of 8 candidates per row
  {
    int rr = tid >> 3, j = tid & 7;
    int code = top8i[rr][j];
    const float4* wr4 = (const float4*)(W + (size_t)code * DIM);
    const float*  xr  = x + (size_t)b * DIM * 256 + t0 + rr;
    double d0 = 0.0, d1 = 0.0, d2 = 0.0, d3 = 0.0;
    for (int d4 = 0; d4 < 128; ++d4) {
      float4 wv = wr4[d4];
      float x0 = xr[(size_t)(d4*4 + 0) * 256];
      float x1 = xr[(size_t)(d4*4 + 1) * 256];
      float x2 = xr[(size_t)(d4*4 + 2) * 256];
      float x3 = xr[(size_t)(d4*4 + 3) * 256];
      d0 = fma((double)x0, (double)wv.x, d0);
      d1 = fma((double)x1, (double)wv.y, d1);
      d2 = fma((double)x2, (double)wv.z, d2);
      d3 = fma((double)x3, (double)wv.w, d3);
    }
    sc8[rr][j] = w2d[code] - 2.0 * ((d0 + d1) + (d2 + d3));
  }
  __syncthreads();

  // ---- final order: sort 8 by (score, index) asc == top_k(-dist) order
  if (tid < MB) {
    double sd[8]; int id_[8];
    #pragma unroll
    for (int k = 0; k < 8; ++k) { sd[k] = sc8[tid][k]; id_[k] = top8i[tid][k]; }
    #pragma unroll
    for (int i = 0; i < 7; ++i)
      #pragma unroll
      for (int jj = 0; jj < 7; ++jj)
        if (jj < 7 - i) {
          bool sw = (sd[jj] > sd[jj+1]) ||
                    (sd[jj] == sd[jj+1] && id_[jj] > id_[jj+1]);
          if (sw) {
            double td = sd[jj]; sd[jj] = sd[jj+1]; sd[jj+1] = td;
            int    tt = id_[jj]; id_[jj] = id_[jj+1]; id_[jj+1] = tt;
          }
        }
    int n = n0 + tid;
    idx3s[tid] = make_int4(id_[0], id_[1], id_[2], 0);
    out[OUT_IDX_OFF + n] = (float)id_[2];
    atomicAdd(&counts[id_[0]], 1);
    atomicAdd(&counts[id_[1]], 1);
    atomicAdd(&counts[id_[2]], 1);
  }
  __syncthreads();

  // ---- Phase E: fused quantize + straight-through + loss
  {
    int rr = tid & 31, g = tid >> 5;       // 8 d-groups of 64 dims
    int4 ii = idx3s[rr];
    const float4* w0 = (const float4*)(W + (size_t)ii.x * DIM);
    const float4* w1 = (const float4*)(W + (size_t)ii.y * DIM);
    const float4* w2 = (const float4*)(W + (size_t)ii.z * DIM);
    const float*  xr = x + (size_t)b * DIM * 256 + t0 + rr;
    float* outq = out + OUT_Q_OFF + (size_t)b * DIM * 256 + t0 + rr;
    float lsum = 0.0f;
    #pragma unroll 4
    for (int d4 = 0; d4 < 16; ++d4) {
      int idx4 = g * 16 + d4;
      float4 a0 = w0[idx4], a1 = w1[idx4], a2 = w2[idx4];
      float qv[4] = { (a0.x + a1.x + a2.x) * (1.0f/3.0f),
                      (a0.y + a1.y + a2.y) * (1.0f/3.0f),
                      (a0.z + a1.z + a2.z) * (1.0f/3.0f),
                      (a0.w + a1.w + a2.w) * (1.0f/3.0f) };
      #pragma unroll
      for (int e = 0; e < 4; ++e) {
        size_t off = (size_t)(idx4 * 4 + e) * 256;
        float xv = xr[off];
        float diff = qv[e] - xv;             // quantized - inp
        outq[off] = xv + diff;               // straight-through value
        lsum += diff * diff;
      }
    }
    for (int o = 32; o > 0; o >>= 1) lsum += __shfl_down(lsum, o);
    if (lane == 0) lred[w] = lsum;
  }
  __syncthreads();
  if (tid == 0)
    atomicAdd(loss_acc, (lred[0] + lred[1]) + (lred[2] + lred[3]));
}

// ---------------- k_final: loss + perplexity
__global__ __launch_bounds__(256) void k_final(
    const int* __restrict__ counts, const float* __restrict__ loss_acc,
    float* __restrict__ out)
{
  int tid = threadIdx.x;
  float ent = 0.0f;
  for (int k = tid; k < KC; k += 256) {
    float p = (float)counts[k] * (1.0f / 16384.0f);
    ent += p * logf(p + 1e-10f);
  }
  for (int o = 32; o > 0; o >>= 1) ent += __shfl_down(ent, o);
  __shared__ float ps[4];
  if ((tid & 63) == 0) ps[tid >> 6] = ent;
  __syncthreads();
  if (tid == 0) {
    float total = (ps[0] + ps[1]) + (ps[2] + ps[3]);
    out[0] = 1.25f * loss_acc[0] * (1.0f / 8388608.0f);  // q + 0.25*e latent
    out[OUT_P_OFF] = expf(-total);
  }
}

extern "C" void kernel_launch(void* const* d_in, const int* in_sizes, int n_in,
                              void* d_out, int out_size, void* d_ws, size_t ws_size,
                              hipStream_t stream) {
  const float* x = (const float*)d_in[0];
  const float* W = (const float*)d_in[1];
  float* out = (float*)d_out;
  char* ws = (char*)d_ws;
  int*            counts   = (int*)(ws + WS_COUNTS);
  float*          loss_acc = (float*)(ws + WS_LOSS);
  double*         w2d      = (double*)(ws + WS_W2D);
  float*          w2f      = (float*)(ws + WS_W2F);
  unsigned short* Wb       = (unsigned short*)(ws + WS_WB);

  hipMemsetAsync(ws, 0, 8448, stream);   // counts + loss accumulator
  k_w2<<<KC / 4, 256, 0, stream>>>(W, w2d, w2f);
  k_reorder<<<512, 256, 0, stream>>>(W, Wb);
  k_main<<<NROWS / MB, 256, 0, stream>>>(x, W, Wb, w2f, w2d, counts, out, loss_acc);
  k_final<<<1, 256, 0, stream>>>(counts, loss_acc, out);
}